// Round 5
// baseline (200.960 us; speedup 1.0000x reference)
//
#include <hip/hip_runtime.h>

// PatchAttacker: B=32 images 512x512x3, N=6 boxes, patch 512x512x3.
// Final pixel = bilinear(patch) of the LAST valid covering patch box, else image.
// v5: hoist per-(image,box) geometry into a 192-thread setup kernel (d_ws).
//     Main kernel reads box params as wave-uniform scalars -> s_load + SALU
//     row rejection (uniform s_cbranch). Kills ~400 redundant VALU insts/thread
//     (geometry was recomputed 8.4M times for 192 unique values; no scalar FP
//     on gfx950, so float geometry could never go SALU in-kernel).
//     Rest unchanged from v4b (proven, absmax 0.0): late predicated nt image
//     loads, batched 4B-aligned patch gathers, LDS transpose + full-line nt
//     stores (WRITE_SIZE == exact output).

#define Bn 32
#define Nn 6
#define Hh 512
#define Ww 512
#define Pp 512

typedef float f32x4 __attribute__((ext_vector_type(4)));
typedef float f32x4u __attribute__((ext_vector_type(4), aligned(4)));
typedef float f32x2u __attribute__((ext_vector_type(2), aligned(4)));

struct BoxP {
    int   y0b, x0b, hI, wI;
    float syscale, winv;
    int   valid, pad;
};

__global__ __launch_bounds__(192) void box_setup_kernel(
    const float* __restrict__ boxes,   // [B,N,4]
    BoxP* __restrict__ bp)             // [B*N]
{
    const int i = threadIdx.x;         // 0..191 == b*Nn+n
    if (i >= Bn * Nn) return;
    const float ymin = boxes[i * 4 + 0];
    const float xmin = boxes[i * 4 + 1];
    const float ymax = boxes[i * 4 + 2];
    const float xmax = boxes[i * 4 + 3];
    const float h  = ymax - ymin;
    const float w  = xmax - xmin;
    const float pw = h * 0.5f;            // SCALE = 0.5
    const float ph = 1.0f * pw;           // ASPECT = 1.0
    const float oy = ymin + h * 0.5f;
    const float ox = xmin + w * 0.5f;
    float yp = fmaxf(oy - ph * 0.5f, 0.0f);
    float xp = fmaxf(ox - pw * 0.5f, 0.0f);
    yp = (yp + ph > (float)Hh) ? ((float)Hh - ph) : yp;
    xp = (xp + pw > (float)Ww) ? ((float)Ww - pw) : xp;

    BoxP p;
    p.y0b = (int)yp;                      // tf.cast truncation (>=0)
    p.x0b = (int)xp;
    p.hI  = (int)ph;
    p.wI  = (int)pw;
    // identical op order to reference: (float)Pp / hf, then multiplied later
    const float hf = (float)(p.hI > 1 ? p.hI : 1);
    const float wf = (float)(p.wI > 1 ? p.wI : 1);
    p.syscale = (float)Pp / hf;
    p.winv    = (float)Pp / wf;
    p.valid   = (ph > 60.0f) ? 1 : 0;     // MIN_PH
    p.pad     = 0;
    bp[i] = p;
}

__global__ __launch_bounds__(256) void patch_attack_kernel(
    const float* __restrict__ images,  // [B,H,W,3]
    const BoxP* __restrict__ bparams,  // [B*N] from setup kernel
    const float* __restrict__ patch,   // [P,P,3]
    float* __restrict__ out)           // [B,H,W,3]
{
    __shared__ float lds[3072];        // 256 threads x 12 floats

    const int tid   = threadIdx.x;
    const int chunk = blockIdx.x * 256 + tid;             // 4-pixel chunks
    // b uniform per block, y uniform per wave (wave = 64 chunks = half a row)
    const int b     = __builtin_amdgcn_readfirstlane(chunk >> 16);
    const int rem   = chunk & 65535;
    const int y     = __builtin_amdgcn_readfirstlane(rem >> 7);
    const int x4    = (rem & 127) << 2;                   // starting x of chunk

    const BoxP* __restrict__ bp = bparams + b * Nn;

    // ---------------- pass 1: coverage resolution (uniform SALU rejection) ----
    int   bid[4]  = {-1, -1, -1, -1};
    int   offL[4] = {0, 0, 0, 0};      // byte offset of low-row 6-float group
    float wxs[4]  = {0.f, 0.f, 0.f, 0.f};
    float wys[4]  = {0.f, 0.f, 0.f, 0.f};

    #pragma unroll
    for (int n = Nn - 1; n >= 0; --n) {   // descending: first hit == last writer
        // all fields wave-uniform -> s_load; row test is SALU + s_cbranch
        const int y0b = bp[n].y0b;
        const int hI  = bp[n].hI;
        const int dy  = y - y0b;
        if (!(bp[n].valid && dy >= 0 && dy < hI)) continue;

        const int   x0b     = bp[n].x0b;
        const int   wI      = bp[n].wI;
        const float syscale = bp[n].syscale;
        const float winv    = bp[n].winv;

        float sy = ((float)dy + 0.5f) * syscale - 0.5f;
        sy = fminf(fmaxf(sy, 0.0f), (float)(Pp - 1));
        int yl = (int)sy;                     // == floor (sy >= 0)
        yl = (yl > Pp - 2) ? (Pp - 2) : yl;   // yh = yl+1 always; wy==1 -> row 511
        const float wyv = sy - (float)yl;
        const int rl = yl * (Pp * 3 * 4);     // row byte offset (6144 B/row)

        #pragma unroll
        for (int j = 0; j < 4; ++j) {
            const int dx = x4 + j - x0b;
            float sx = ((float)dx + 0.5f) * winv - 0.5f;
            sx = fminf(fmaxf(sx, 0.0f), (float)(Pp - 1));
            int xl = (int)sx;
            xl = (xl > Pp - 2) ? (Pp - 2) : xl;   // xh = xl+1; wx==1 -> col 511
            const float wxv = sx - (float)xl;
            const bool hit = (dx >= 0) & (dx < wI) & (bid[j] < 0);
            if (hit) {                 // select chains, no divergence cost
                bid[j]  = n;
                offL[j] = rl + xl * 12;
                wxs[j]  = wxv;
                wys[j]  = wyv;
            }
        }
    }

    // -------- issue image loads EARLY (consumed at the very end) --------
    const bool c0 = bid[0] >= 0, c1 = bid[1] >= 0, c2 = bid[2] >= 0, c3 = bid[3] >= 0;
    f32x4 i0 = {0.f, 0.f, 0.f, 0.f}, i1 = i0, i2 = i0;
    if (!(c0 & c1 & c2 & c3)) {
        const f32x4* __restrict__ ip = (const f32x4*)(images + (size_t)chunk * 12);
        i0 = __builtin_nontemporal_load(ip + 0);
        i1 = __builtin_nontemporal_load(ip + 1);
        i2 = __builtin_nontemporal_load(ip + 2);
    }

    // ---------------- pass 2: batched patch gathers + bilinear ----------------
    float pr[12] = {0.f, 0.f, 0.f, 0.f, 0.f, 0.f, 0.f, 0.f, 0.f, 0.f, 0.f, 0.f};
    const char* __restrict__ pbytes = (const char*)patch;
    if (__any(c0 | c1 | c2 | c3)) {
        // uncovered lanes read patch[0..24) harmlessly (offL==0).
        // offL is a multiple of 4 -> explicitly 4B-aligned vector loads.
        float A[4][6], Bv[4][6];
        #pragma unroll
        for (int j = 0; j < 4; ++j) {
            const f32x4u a0 = *(const f32x4u*)(pbytes + offL[j]);          // yl: x{l,l+1}
            const f32x2u a1 = *(const f32x2u*)(pbytes + offL[j] + 16);
            const f32x4u b0 = *(const f32x4u*)(pbytes + offL[j] + 6144);   // yl+1
            const f32x2u b1 = *(const f32x2u*)(pbytes + offL[j] + 6160);
            A[j][0] = a0.x;  A[j][1] = a0.y;  A[j][2] = a0.z;
            A[j][3] = a0.w;  A[j][4] = a1.x;  A[j][5] = a1.y;
            Bv[j][0] = b0.x; Bv[j][1] = b0.y; Bv[j][2] = b0.z;
            Bv[j][3] = b0.w; Bv[j][4] = b1.x; Bv[j][5] = b1.y;
        }
        #pragma unroll
        for (int j = 0; j < 4; ++j) {
            const float wyv = wys[j], wxv = wxs[j];
            const float omy = 1.0f - wyv, omx = 1.0f - wxv;
            #pragma unroll
            for (int c = 0; c < 3; ++c) {
                // same op order as reference: rows over y, then x
                pr[j * 3 + c] = (A[j][c]     * omy + Bv[j][c]     * wyv) * omx
                              + (A[j][3 + c] * omy + Bv[j][3 + c] * wyv) * wxv;
            }
        }
    }

    // ---------------- final select (image loads consumed here) ----------------
    const float img[12] = {i0.x, i0.y, i0.z, i0.w,
                           i1.x, i1.y, i1.z, i1.w,
                           i2.x, i2.y, i2.z, i2.w};
    float r[12];
    #pragma unroll
    for (int j = 0; j < 4; ++j) {
        const bool cv = bid[j] >= 0;
        r[j * 3 + 0] = cv ? pr[j * 3 + 0] : img[j * 3 + 0];
        r[j * 3 + 1] = cv ? pr[j * 3 + 1] : img[j * 3 + 1];
        r[j * 3 + 2] = cv ? pr[j * 3 + 2] : img[j * 3 + 2];
    }

    // ---- LDS block-transpose -> full-line nt stores (proven in v3) ----
    f32x4* __restrict__ lw = (f32x4*)(lds + tid * 12);
    f32x4 w0, w1, w2;
    w0.x = r[0];  w0.y = r[1];  w0.z = r[2];  w0.w = r[3];
    w1.x = r[4];  w1.y = r[5];  w1.z = r[6];  w1.w = r[7];
    w2.x = r[8];  w2.y = r[9];  w2.z = r[10]; w2.w = r[11];
    lw[0] = w0;
    lw[1] = w1;
    lw[2] = w2;

    __syncthreads();

    const size_t blk_f = (size_t)blockIdx.x * 3072;
    #pragma unroll
    for (int k = 0; k < 3; ++k) {
        const f32x4 v = *(const f32x4*)(lds + k * 1024 + tid * 4);
        __builtin_nontemporal_store(
            v, (f32x4*)(out + blk_f + (size_t)k * 1024 + (size_t)tid * 4));
    }
}

extern "C" void kernel_launch(void* const* d_in, const int* in_sizes, int n_in,
                              void* d_out, int out_size, void* d_ws, size_t ws_size,
                              hipStream_t stream) {
    const float* images = (const float*)d_in[0];
    const float* boxes  = (const float*)d_in[1];
    const float* patch  = (const float*)d_in[2];
    float* out = (float*)d_out;
    BoxP* bp = (BoxP*)d_ws;            // needs 32*6*32 B = 6 KB of workspace

    box_setup_kernel<<<1, 192, 0, stream>>>(boxes, bp);

    const int total_chunks = Bn * Hh * Ww / 4;  // 2,097,152
    const int block = 256;
    const int grid  = total_chunks / block;     // 8192

    patch_attack_kernel<<<grid, block, 0, stream>>>(images, bp, patch, out);
}